// Round 4
// baseline (558.263 us; speedup 1.0000x reference)
//
#include <hip/hip_runtime.h>
#include <math.h>

#define T_    10
#define NB_   10
#define C1_   20            // 2*NB
#define SX_   1200
#define OX_   302
#define S2_   (OX_*OX_)     // 91204
#define NP_   300           // pooled interior size
#define ND_   5
#define FLAT_ (NB_*S2_)     // 912040
#define XBLK_FC1 446        // 446*256*2 = 228352 >= 228010 : exactly 2 iters/thread

typedef float f4 __attribute__((ext_vector_type(4)));

// Fused: 1x1 conv1 (+zero-pad) -> 4x4 maxpool -> 1x1 conv2 (interior), plus
// border fill on the z==10 grid slice.
// DIAGNOSTIC (this round only): body repeated over 4 distinct x-slices
// (tr=(t+3..0)%10); reps 1..3 kept live via asm sink; rep 0 (tr==t) is real.
__global__ __launch_bounds__(256) void k_convpool(const float* __restrict__ x,
                                                  const float* __restrict__ w1,
                                                  const float* __restrict__ b1,
                                                  const float* __restrict__ w2,
                                                  const float* __restrict__ b2,
                                                  float* __restrict__ dynb,
                                                  float* __restrict__ feat) {
    const int t = blockIdx.z;
    if (t == T_) {
        // border fill: x5 border pixels have value conv2_b[channel]
        int s = (blockIdx.y * 5 + blockIdx.x) * 256 + threadIdx.y * 64 + threadIdx.x;
        if (s >= S2_) return;
        int ox = s / OX_, oy = s % OX_;
        if (ox != 0 && ox != OX_ - 1 && oy != 0 && oy != OX_ - 1) return;
#pragma unroll
        for (int d = 0; d < ND_; ++d) {
            float v = b2[d];
#pragma unroll
            for (int tt = 0; tt < T_; ++tt) dynb[(tt * ND_ + d) * S2_ + s] = v;
        }
#pragma unroll
        for (int c = 0; c < ND_; ++c) feat[(ND_ + c) * S2_ + s] = b2[ND_ + c];
        return;
    }

    const int lane  = threadIdx.x;                  // 0..63
    const int obase = blockIdx.x * 63;              // 0,63,126,189,252
    const int px    = blockIdx.y * 4 + threadIdx.y; // 0..299

    const int lc  = 4 * (obase - 1 + lane);         // this lane's aligned column base
    const int lcc = lc < 0 ? 0 : (lc > SX_ - 4 ? SX_ - 4 : lc);
    const bool m3valid = (lc >= 0);

    const int rs = (px > 0) ? 4 * px - 1 : 0;
    const int re = 4 * px + 2;

    float pool012[C1_], pool3[C1_];
    float sink = 0.f;

#pragma unroll 1
    for (int rep = 3; rep >= 0; --rep) {
        const int tr = (t + rep) % T_;              // rep==0 -> tr==t (real pass)
        const float* xt = x + (size_t)tr * NB_ * SX_ * SX_;
#pragma unroll
        for (int o = 0; o < C1_; ++o) { pool012[o] = -3.0e38f; pool3[o] = -3.0e38f; }

        for (int row = rs; row <= re; ++row) {
            f4 xv[NB_];
#pragma unroll
            for (int c = 0; c < NB_; ++c)
                xv[c] = *(const f4*)(xt + ((size_t)c * SX_ + row) * SX_ + lcc);
#pragma unroll
            for (int o = 0; o < C1_; ++o) {
                float bb = b1[o];
                float h0 = bb, h1 = bb, h2 = bb, h3 = bb;
#pragma unroll
                for (int c = 0; c < NB_; ++c) {
                    float w = w1[o * NB_ + c];
                    h0 = fmaf(w, xv[c].x, h0);
                    h1 = fmaf(w, xv[c].y, h1);
                    h2 = fmaf(w, xv[c].z, h2);
                    h3 = fmaf(w, xv[c].w, h3);
                }
                pool012[o] = fmaxf(pool012[o], fmaxf(fmaxf(h0, h1), h2));
                pool3[o]   = fmaxf(pool3[o], h3);
            }
        }
        if (rep > 0) {
#pragma unroll
            for (int o = 0; o < C1_; ++o) sink += pool012[o] + pool3[o];
        }
    }
    asm volatile("" :: "v"(sink));                  // keep reps 1..3 live (no DCE)

    const int py = obase + lane;
    const bool edge = (px == 0) | (py == 0);
    float pool[C1_];
#pragma unroll
    for (int o = 0; o < C1_; ++o) {
        float m3    = m3valid ? pool3[o] : -3.0e38f;
        float other = __shfl_down(pool012[o], 1, 64);   // lane k+1's cols 0..2
        float p = fmaxf(m3, other);
        if (edge) p = fmaxf(p, b1[o]);                  // zero-pad -> conv1 bias
        pool[o] = p;
    }

    if (lane < 63 && py < NP_) {
        int s = (px + 1) * OX_ + (py + 1);
        float out[NB_];
#pragma unroll
        for (int o2 = 0; o2 < NB_; ++o2) {
            float a = b2[o2];
#pragma unroll
            for (int o = 0; o < C1_; ++o) a = fmaf(w2[o2 * C1_ + o], pool[o], a);
            out[o2] = a;
        }
#pragma unroll
        for (int d = 0; d < ND_; ++d) dynb[(t * ND_ + d) * S2_ + s] = out[d];
        if (t == T_ - 1) {
#pragma unroll
            for (int c = 0; c < ND_; ++c) feat[(ND_ + c) * S2_ + s] = out[ND_ + c];
        }
    }
}

// Scrambled-reshape scalar LSTM: sequence p in [0,91204), feature d in [0,5).
// Native exp (v_exp_f32) + rcp instead of libm expf/tanhf.
__global__ __launch_bounds__(256) void k_lstm(const float* __restrict__ dynb,
                                              const float* __restrict__ w_ih,
                                              const float* __restrict__ w_hh,
                                              const float* __restrict__ b_ih,
                                              const float* __restrict__ b_hh,
                                              float* __restrict__ feat) {
    int i = blockIdx.x * 256 + threadIdx.x;
    if (i >= S2_ * ND_) return;
    int p = i / ND_, d = i - p * ND_;

    float wi[4], wh[4], bb[4];
#pragma unroll
    for (int g = 0; g < 4; ++g) {
        wi[g] = w_ih[d * 4 + g];
        wh[g] = w_hh[d * 4 + g];
        bb[g] = b_ih[d * 4 + g] + b_hh[d * 4 + g];
    }
    float h = 0.f, cc = 0.f;
#pragma unroll 1
    for (int tt = 0; tt < T_; ++tt) {
        float xt = dynb[p * (T_ * ND_) + tt * ND_ + d];
        float g0 = fmaf(xt, wi[0], fmaf(h, wh[0], bb[0]));
        float g1 = fmaf(xt, wi[1], fmaf(h, wh[1], bb[1]));
        float g2 = fmaf(xt, wi[2], fmaf(h, wh[2], bb[2]));
        float g3 = fmaf(xt, wi[3], fmaf(h, wh[3], bb[3]));
        float ig = __builtin_amdgcn_rcpf(1.f + __expf(-g0));
        float fg = __builtin_amdgcn_rcpf(1.f + __expf(-g1));
        float gg = fmaf(2.f, __builtin_amdgcn_rcpf(1.f + __expf(-2.f * g2)), -1.f);
        float og = __builtin_amdgcn_rcpf(1.f + __expf(-g3));
        cc = fg * cc + ig * gg;
        float th = fmaf(2.f, __builtin_amdgcn_rcpf(1.f + __expf(-2.f * cc)), -1.f);
        h = og * th;
    }
    feat[d * S2_ + p] = h;
}

// fc1 partial GEMV: grid (446, 2); every thread does EXACTLY 2 i4-iterations
// (second masked at the very tail). Block (bx,jy) accumulates 32 outputs.
__global__ __launch_bounds__(256) void k_fc1(const float* __restrict__ feat,
                                             const float* __restrict__ w,
                                             float* __restrict__ partial) {
    __shared__ float red[4][32];
    const int tid = threadIdx.x;
    const int jbase = blockIdx.y * 32;
    const int NI4 = FLAT_ / 4;                 // 228010
    const int HALF = XBLK_FC1 * 256;           // 114176
    float acc[32];
#pragma unroll
    for (int j = 0; j < 32; ++j) acc[j] = 0.f;
    const float* wb = w + (size_t)jbase * FLAT_;

    int i4a = blockIdx.x * 256 + tid;          // always < NI4
    int i4b = i4a + HALF;                      // mask vs NI4
    {
        f4 f = *(const f4*)(feat + (size_t)i4a * 4);
#pragma unroll
        for (int j = 0; j < 32; ++j) {
            f4 wv = *(const f4*)(wb + (size_t)j * FLAT_ + (size_t)i4a * 4);
            acc[j] = fmaf(wv.x, f.x, acc[j]);
            acc[j] = fmaf(wv.y, f.y, acc[j]);
            acc[j] = fmaf(wv.z, f.z, acc[j]);
            acc[j] = fmaf(wv.w, f.w, acc[j]);
        }
    }
    if (i4b < NI4) {
        f4 f = *(const f4*)(feat + (size_t)i4b * 4);
#pragma unroll
        for (int j = 0; j < 32; ++j) {
            f4 wv = *(const f4*)(wb + (size_t)j * FLAT_ + (size_t)i4b * 4);
            acc[j] = fmaf(wv.x, f.x, acc[j]);
            acc[j] = fmaf(wv.y, f.y, acc[j]);
            acc[j] = fmaf(wv.z, f.z, acc[j]);
            acc[j] = fmaf(wv.w, f.w, acc[j]);
        }
    }
    int lane = tid & 63, wid = tid >> 6;
#pragma unroll
    for (int j = 0; j < 32; ++j) {
        float v = acc[j];
#pragma unroll
        for (int off = 32; off >= 1; off >>= 1) v += __shfl_xor(v, off, 64);
        if (lane == 0) red[wid][j] = v;
    }
    __syncthreads();
    if (tid < 32) {
        float s = red[0][tid] + red[1][tid] + red[2][tid] + red[3][tid];
        partial[blockIdx.x * 64 + jbase + tid] = s;
    }
}

// Final reduce + fc2/relu/fc3/fc4 -> 3 outputs. Single block.
__global__ __launch_bounds__(256) void k_head(const float* __restrict__ partial,
                                              const float* __restrict__ fc1_b,
                                              const float* __restrict__ fc2_w,
                                              const float* __restrict__ fc2_b,
                                              const float* __restrict__ fc3_w,
                                              const float* __restrict__ fc3_b,
                                              const float* __restrict__ fc4_w,
                                              const float* __restrict__ fc4_b,
                                              float* __restrict__ out) {
    __shared__ float r4[256];
    __shared__ float y1[64], y2[64], y3[16];
    int tid = threadIdx.x;
    int j = tid & 63, q = tid >> 6;
    float s = 0.f;
    for (int b = q; b < XBLK_FC1; b += 4) s += partial[b * 64 + j];
    r4[tid] = s;
    __syncthreads();
    if (tid < 64)
        y1[tid] = r4[tid] + r4[64 + tid] + r4[128 + tid] + r4[192 + tid] + fc1_b[tid];
    __syncthreads();
    if (tid < 64) {
        float a = fc2_b[tid];
#pragma unroll
        for (int k = 0; k < 64; ++k) a = fmaf(fc2_w[tid * 64 + k], y1[k], a);
        y2[tid] = fmaxf(a, 0.f);
    }
    __syncthreads();
    if (tid < 16) {
        float a = fc3_b[tid];
#pragma unroll
        for (int k = 0; k < 64; ++k) a = fmaf(fc3_w[tid * 64 + k], y2[k], a);
        y3[tid] = a;
    }
    __syncthreads();
    if (tid < 3) {
        float a = fc4_b[tid];
#pragma unroll
        for (int k = 0; k < 16; ++k) a = fmaf(fc4_w[tid * 16 + k], y3[k], a);
        out[tid] = a;
    }
}

extern "C" void kernel_launch(void* const* d_in, const int* in_sizes, int n_in,
                              void* d_out, int out_size, void* d_ws, size_t ws_size,
                              hipStream_t stream) {
    const float* x     = (const float*)d_in[0];
    const float* w1    = (const float*)d_in[1];
    const float* b1    = (const float*)d_in[2];
    const float* w2    = (const float*)d_in[3];
    const float* b2    = (const float*)d_in[4];
    const float* w_ih  = (const float*)d_in[5];
    const float* w_hh  = (const float*)d_in[6];
    const float* b_ih  = (const float*)d_in[7];
    const float* b_hh  = (const float*)d_in[8];
    const float* fc1_w = (const float*)d_in[9];
    const float* fc1_b = (const float*)d_in[10];
    const float* fc2_w = (const float*)d_in[11];
    const float* fc2_b = (const float*)d_in[12];
    const float* fc3_w = (const float*)d_in[13];
    const float* fc3_b = (const float*)d_in[14];
    const float* fc4_w = (const float*)d_in[15];
    const float* fc4_b = (const float*)d_in[16];

    float* ws      = (float*)d_ws;
    float* dynb    = ws;                          // [10][5][91204]
    float* feat    = ws + (size_t)T_ * ND_ * S2_; // [10][91204]
    float* partial = feat + FLAT_;                // [446][64]

    hipLaunchKernelGGL(k_convpool, dim3(5, 75, T_ + 1), dim3(64, 4), 0, stream,
                       x, w1, b1, w2, b2, dynb, feat);
    hipLaunchKernelGGL(k_lstm, dim3((S2_ * ND_ + 255) / 256), dim3(256), 0, stream,
                       dynb, w_ih, w_hh, b_ih, b_hh, feat);
    hipLaunchKernelGGL(k_fc1, dim3(XBLK_FC1, 2), dim3(256), 0, stream,
                       feat, fc1_w, partial);
    hipLaunchKernelGGL(k_head, dim3(1), dim3(256), 0, stream,
                       partial, fc1_b, fc2_w, fc2_b, fc3_w, fc3_b, fc4_w, fc4_b,
                       (float*)d_out);
}

// Round 5
// 322.186 us; speedup vs baseline: 1.7327x; 1.7327x over previous
//
#include <hip/hip_runtime.h>
#include <math.h>

#define T_    10
#define NB_   10
#define C1_   20            // 2*NB
#define SX_   1200
#define OX_   302
#define S2_   (OX_*OX_)     // 91204
#define NP_   300           // pooled interior size
#define ND_   5
#define FLAT_ (NB_*S2_)     // 912040
#define XBLK_FC1 446        // 446*256*2 = 228352 >= 228010 : exactly 2 iters/thread

typedef float f4 __attribute__((ext_vector_type(4)));

static __device__ __forceinline__ f4 splat4(float v) { return (f4){v, v, v, v}; }

// Fused: 1x1 conv1 (+zero-pad) -> 4x4 maxpool -> 1x1 conv2 (interior), plus
// border fill on the z==10 grid slice.
// __launch_bounds__(256,4): 128-VGPR budget so xv[40]+pool[40] stay in VGPRs
// (at 64 VGPR the compiler shuffles arrays through AGPRs = hidden VALU cost).
__global__ __launch_bounds__(256, 4) void k_convpool(const float* __restrict__ x,
                                                     const float* __restrict__ w1,
                                                     const float* __restrict__ b1,
                                                     const float* __restrict__ w2,
                                                     const float* __restrict__ b2,
                                                     float* __restrict__ dynb,
                                                     float* __restrict__ feat) {
    const int t = blockIdx.z;
    if (t == T_) {
        // border fill: x5 border pixels have value conv2_b[channel]
        int s = (blockIdx.y * 5 + blockIdx.x) * 256 + threadIdx.y * 64 + threadIdx.x;
        if (s >= S2_) return;
        int ox = s / OX_, oy = s % OX_;
        if (ox != 0 && ox != OX_ - 1 && oy != 0 && oy != OX_ - 1) return;
#pragma unroll
        for (int d = 0; d < ND_; ++d) {
            float v = b2[d];
#pragma unroll
            for (int tt = 0; tt < T_; ++tt) dynb[(tt * ND_ + d) * S2_ + s] = v;
        }
#pragma unroll
        for (int c = 0; c < ND_; ++c) feat[(ND_ + c) * S2_ + s] = b2[ND_ + c];
        return;
    }

    const int lane  = threadIdx.x;                  // 0..63
    const int obase = blockIdx.x * 63;              // 0,63,126,189,252
    const int px    = blockIdx.y * 4 + threadIdx.y; // 0..299

    const int lc  = 4 * (obase - 1 + lane);         // this lane's aligned column base
    const int lcc = lc < 0 ? 0 : (lc > SX_ - 4 ? SX_ - 4 : lc);
    const bool m3valid = (lc >= 0);

    float pool012[C1_], pool3[C1_];
#pragma unroll
    for (int o = 0; o < C1_; ++o) { pool012[o] = -3.0e38f; pool3[o] = -3.0e38f; }

    const int rs = (px > 0) ? 4 * px - 1 : 0;
    const int re = 4 * px + 2;
    const float* xt = x + (size_t)t * NB_ * SX_ * SX_;

    for (int row = rs; row <= re; ++row) {
        f4 xv[NB_];
#pragma unroll
        for (int c = 0; c < NB_; ++c)
            xv[c] = *(const f4*)(xt + ((size_t)c * SX_ + row) * SX_ + lcc);
#pragma unroll
        for (int o = 0; o < C1_; ++o) {
            f4 h = splat4(b1[o]);
#pragma unroll
            for (int c = 0; c < NB_; ++c)
                h = __builtin_elementwise_fma(splat4(w1[o * NB_ + c]), xv[c], h);
            pool012[o] = fmaxf(pool012[o], fmaxf(fmaxf(h.x, h.y), h.z));  // v_max3
            pool3[o]   = fmaxf(pool3[o], h.w);
        }
    }

    const int py = obase + lane;
    const bool edge = (px == 0) | (py == 0);
    float pool[C1_];
#pragma unroll
    for (int o = 0; o < C1_; ++o) {
        float m3    = m3valid ? pool3[o] : -3.0e38f;
        float other = __shfl_down(pool012[o], 1, 64);   // lane k+1's cols 0..2
        float p = fmaxf(m3, other);
        if (edge) p = fmaxf(p, b1[o]);                  // zero-pad -> conv1 bias
        pool[o] = p;
    }

    if (lane < 63 && py < NP_) {
        int s = (px + 1) * OX_ + (py + 1);
        float out[NB_];
#pragma unroll
        for (int o2 = 0; o2 < NB_; ++o2) {
            float a = b2[o2];
#pragma unroll
            for (int o = 0; o < C1_; ++o) a = fmaf(w2[o2 * C1_ + o], pool[o], a);
            out[o2] = a;
        }
#pragma unroll
        for (int d = 0; d < ND_; ++d) dynb[(t * ND_ + d) * S2_ + s] = out[d];
        if (t == T_ - 1) {
#pragma unroll
            for (int c = 0; c < ND_; ++c) feat[(ND_ + c) * S2_ + s] = out[ND_ + c];
        }
    }
}

// Scrambled-reshape scalar LSTM: sequence p in [0,91204), feature d in [0,5).
// Native exp (v_exp_f32) + rcp instead of libm expf/tanhf.
__global__ __launch_bounds__(256) void k_lstm(const float* __restrict__ dynb,
                                              const float* __restrict__ w_ih,
                                              const float* __restrict__ w_hh,
                                              const float* __restrict__ b_ih,
                                              const float* __restrict__ b_hh,
                                              float* __restrict__ feat) {
    int i = blockIdx.x * 256 + threadIdx.x;
    if (i >= S2_ * ND_) return;
    int p = i / ND_, d = i - p * ND_;

    float wi[4], wh[4], bb[4];
#pragma unroll
    for (int g = 0; g < 4; ++g) {
        wi[g] = w_ih[d * 4 + g];
        wh[g] = w_hh[d * 4 + g];
        bb[g] = b_ih[d * 4 + g] + b_hh[d * 4 + g];
    }
    float h = 0.f, cc = 0.f;
#pragma unroll 1
    for (int tt = 0; tt < T_; ++tt) {
        float xt = dynb[p * (T_ * ND_) + tt * ND_ + d];
        float g0 = fmaf(xt, wi[0], fmaf(h, wh[0], bb[0]));
        float g1 = fmaf(xt, wi[1], fmaf(h, wh[1], bb[1]));
        float g2 = fmaf(xt, wi[2], fmaf(h, wh[2], bb[2]));
        float g3 = fmaf(xt, wi[3], fmaf(h, wh[3], bb[3]));
        float ig = __builtin_amdgcn_rcpf(1.f + __expf(-g0));
        float fg = __builtin_amdgcn_rcpf(1.f + __expf(-g1));
        float gg = fmaf(2.f, __builtin_amdgcn_rcpf(1.f + __expf(-2.f * g2)), -1.f);
        float og = __builtin_amdgcn_rcpf(1.f + __expf(-g3));
        cc = fg * cc + ig * gg;
        float th = fmaf(2.f, __builtin_amdgcn_rcpf(1.f + __expf(-2.f * cc)), -1.f);
        h = og * th;
    }
    feat[d * S2_ + p] = h;
}

// fc1 partial GEMV: grid (446, 2); every thread does EXACTLY 2 i4-iterations
// (second masked at the very tail). Block (bx,jy) accumulates 32 outputs.
__global__ __launch_bounds__(256) void k_fc1(const float* __restrict__ feat,
                                             const float* __restrict__ w,
                                             float* __restrict__ partial) {
    __shared__ float red[4][32];
    const int tid = threadIdx.x;
    const int jbase = blockIdx.y * 32;
    const int NI4 = FLAT_ / 4;                 // 228010
    const int HALF = XBLK_FC1 * 256;           // 114176
    float acc[32];
#pragma unroll
    for (int j = 0; j < 32; ++j) acc[j] = 0.f;
    const float* wb = w + (size_t)jbase * FLAT_;

    int i4a = blockIdx.x * 256 + tid;          // always < NI4
    int i4b = i4a + HALF;                      // mask vs NI4
    {
        f4 f = *(const f4*)(feat + (size_t)i4a * 4);
#pragma unroll
        for (int j = 0; j < 32; ++j) {
            f4 wv = *(const f4*)(wb + (size_t)j * FLAT_ + (size_t)i4a * 4);
            acc[j] = fmaf(wv.x, f.x, acc[j]);
            acc[j] = fmaf(wv.y, f.y, acc[j]);
            acc[j] = fmaf(wv.z, f.z, acc[j]);
            acc[j] = fmaf(wv.w, f.w, acc[j]);
        }
    }
    if (i4b < NI4) {
        f4 f = *(const f4*)(feat + (size_t)i4b * 4);
#pragma unroll
        for (int j = 0; j < 32; ++j) {
            f4 wv = *(const f4*)(wb + (size_t)j * FLAT_ + (size_t)i4b * 4);
            acc[j] = fmaf(wv.x, f.x, acc[j]);
            acc[j] = fmaf(wv.y, f.y, acc[j]);
            acc[j] = fmaf(wv.z, f.z, acc[j]);
            acc[j] = fmaf(wv.w, f.w, acc[j]);
        }
    }
    int lane = tid & 63, wid = tid >> 6;
#pragma unroll
    for (int j = 0; j < 32; ++j) {
        float v = acc[j];
#pragma unroll
        for (int off = 32; off >= 1; off >>= 1) v += __shfl_xor(v, off, 64);
        if (lane == 0) red[wid][j] = v;
    }
    __syncthreads();
    if (tid < 32) {
        float s = red[0][tid] + red[1][tid] + red[2][tid] + red[3][tid];
        partial[blockIdx.x * 64 + jbase + tid] = s;
    }
}

// Final reduce + fc2/relu/fc3/fc4 -> 3 outputs. Single block.
__global__ __launch_bounds__(256) void k_head(const float* __restrict__ partial,
                                              const float* __restrict__ fc1_b,
                                              const float* __restrict__ fc2_w,
                                              const float* __restrict__ fc2_b,
                                              const float* __restrict__ fc3_w,
                                              const float* __restrict__ fc3_b,
                                              const float* __restrict__ fc4_w,
                                              const float* __restrict__ fc4_b,
                                              float* __restrict__ out) {
    __shared__ float r4[256];
    __shared__ float y1[64], y2[64], y3[16];
    int tid = threadIdx.x;
    int j = tid & 63, q = tid >> 6;
    float s = 0.f;
    for (int b = q; b < XBLK_FC1; b += 4) s += partial[b * 64 + j];
    r4[tid] = s;
    __syncthreads();
    if (tid < 64)
        y1[tid] = r4[tid] + r4[64 + tid] + r4[128 + tid] + r4[192 + tid] + fc1_b[tid];
    __syncthreads();
    if (tid < 64) {
        float a = fc2_b[tid];
#pragma unroll
        for (int k = 0; k < 64; ++k) a = fmaf(fc2_w[tid * 64 + k], y1[k], a);
        y2[tid] = fmaxf(a, 0.f);
    }
    __syncthreads();
    if (tid < 16) {
        float a = fc3_b[tid];
#pragma unroll
        for (int k = 0; k < 64; ++k) a = fmaf(fc3_w[tid * 64 + k], y2[k], a);
        y3[tid] = a;
    }
    __syncthreads();
    if (tid < 3) {
        float a = fc4_b[tid];
#pragma unroll
        for (int k = 0; k < 16; ++k) a = fmaf(fc4_w[tid * 16 + k], y3[k], a);
        out[tid] = a;
    }
}

extern "C" void kernel_launch(void* const* d_in, const int* in_sizes, int n_in,
                              void* d_out, int out_size, void* d_ws, size_t ws_size,
                              hipStream_t stream) {
    const float* x     = (const float*)d_in[0];
    const float* w1    = (const float*)d_in[1];
    const float* b1    = (const float*)d_in[2];
    const float* w2    = (const float*)d_in[3];
    const float* b2    = (const float*)d_in[4];
    const float* w_ih  = (const float*)d_in[5];
    const float* w_hh  = (const float*)d_in[6];
    const float* b_ih  = (const float*)d_in[7];
    const float* b_hh  = (const float*)d_in[8];
    const float* fc1_w = (const float*)d_in[9];
    const float* fc1_b = (const float*)d_in[10];
    const float* fc2_w = (const float*)d_in[11];
    const float* fc2_b = (const float*)d_in[12];
    const float* fc3_w = (const float*)d_in[13];
    const float* fc3_b = (const float*)d_in[14];
    const float* fc4_w = (const float*)d_in[15];
    const float* fc4_b = (const float*)d_in[16];

    float* ws      = (float*)d_ws;
    float* dynb    = ws;                          // [10][5][91204]
    float* feat    = ws + (size_t)T_ * ND_ * S2_; // [10][91204]
    float* partial = feat + FLAT_;                // [446][64]

    hipLaunchKernelGGL(k_convpool, dim3(5, 75, T_ + 1), dim3(64, 4), 0, stream,
                       x, w1, b1, w2, b2, dynb, feat);
    hipLaunchKernelGGL(k_lstm, dim3((S2_ * ND_ + 255) / 256), dim3(256), 0, stream,
                       dynb, w_ih, w_hh, b_ih, b_hh, feat);
    hipLaunchKernelGGL(k_fc1, dim3(XBLK_FC1, 2), dim3(256), 0, stream,
                       feat, fc1_w, partial);
    hipLaunchKernelGGL(k_head, dim3(1), dim3(256), 0, stream,
                       partial, fc1_b, fc2_w, fc2_b, fc3_w, fc3_b, fc4_w, fc4_b,
                       (float*)d_out);
}

// Round 6
// 225.664 us; speedup vs baseline: 2.4739x; 1.4277x over previous
//
#include <hip/hip_runtime.h>
#include <math.h>

#define T_    10
#define NB_   10
#define C1_   20            // 2*NB
#define SX_   1200
#define OX_   302
#define S2_   (OX_*OX_)     // 91204
#define NP_   300           // pooled interior size
#define ND_   5
#define FLAT_ (NB_*S2_)     // 912040
#define XBLK_FC1 446        // 446*256*2 = 228352 >= 228010 : exactly 2 iters/thread

typedef float f4 __attribute__((ext_vector_type(4)));

// Fused: 1x1 conv1 (+zero-pad) -> 4x4 maxpool -> 1x1 conv2 (interior), plus
// border fill on the z==10 grid slice. SCALAR fmaf body (R2 form, verified
// fastest); single change vs R2: __launch_bounds__(256,4) -> 128-VGPR budget
// so xv[40]+pool[40] live set fits without AGPR-copy spills.
__global__ __launch_bounds__(256, 4) void k_convpool(const float* __restrict__ x,
                                                     const float* __restrict__ w1,
                                                     const float* __restrict__ b1,
                                                     const float* __restrict__ w2,
                                                     const float* __restrict__ b2,
                                                     float* __restrict__ dynb,
                                                     float* __restrict__ feat) {
    const int t = blockIdx.z;
    if (t == T_) {
        // border fill: x5 border pixels have value conv2_b[channel]
        int s = (blockIdx.y * 5 + blockIdx.x) * 256 + threadIdx.y * 64 + threadIdx.x;
        if (s >= S2_) return;
        int ox = s / OX_, oy = s % OX_;
        if (ox != 0 && ox != OX_ - 1 && oy != 0 && oy != OX_ - 1) return;
#pragma unroll
        for (int d = 0; d < ND_; ++d) {
            float v = b2[d];
#pragma unroll
            for (int tt = 0; tt < T_; ++tt) dynb[(tt * ND_ + d) * S2_ + s] = v;
        }
#pragma unroll
        for (int c = 0; c < ND_; ++c) feat[(ND_ + c) * S2_ + s] = b2[ND_ + c];
        return;
    }

    const int lane  = threadIdx.x;                  // 0..63
    const int obase = blockIdx.x * 63;              // 0,63,126,189,252
    const int px    = blockIdx.y * 4 + threadIdx.y; // 0..299

    const int lc  = 4 * (obase - 1 + lane);         // this lane's aligned column base
    const int lcc = lc < 0 ? 0 : (lc > SX_ - 4 ? SX_ - 4 : lc);
    const bool m3valid = (lc >= 0);

    float pool012[C1_], pool3[C1_];
#pragma unroll
    for (int o = 0; o < C1_; ++o) { pool012[o] = -3.0e38f; pool3[o] = -3.0e38f; }

    const int rs = (px > 0) ? 4 * px - 1 : 0;
    const int re = 4 * px + 2;
    const float* xt = x + (size_t)t * NB_ * SX_ * SX_;

    for (int row = rs; row <= re; ++row) {
        f4 xv[NB_];
#pragma unroll
        for (int c = 0; c < NB_; ++c)
            xv[c] = *(const f4*)(xt + ((size_t)c * SX_ + row) * SX_ + lcc);
#pragma unroll
        for (int o = 0; o < C1_; ++o) {
            float bb = b1[o];
            float h0 = bb, h1 = bb, h2 = bb, h3 = bb;
#pragma unroll
            for (int c = 0; c < NB_; ++c) {
                float w = w1[o * NB_ + c];
                h0 = fmaf(w, xv[c].x, h0);
                h1 = fmaf(w, xv[c].y, h1);
                h2 = fmaf(w, xv[c].z, h2);
                h3 = fmaf(w, xv[c].w, h3);
            }
            pool012[o] = fmaxf(pool012[o], fmaxf(fmaxf(h0, h1), h2));
            pool3[o]   = fmaxf(pool3[o], h3);
        }
    }

    const int py = obase + lane;
    const bool edge = (px == 0) | (py == 0);
    float pool[C1_];
#pragma unroll
    for (int o = 0; o < C1_; ++o) {
        float m3    = m3valid ? pool3[o] : -3.0e38f;
        float other = __shfl_down(pool012[o], 1, 64);   // lane k+1's cols 0..2
        float p = fmaxf(m3, other);
        if (edge) p = fmaxf(p, b1[o]);                  // zero-pad -> conv1 bias
        pool[o] = p;
    }

    if (lane < 63 && py < NP_) {
        int s = (px + 1) * OX_ + (py + 1);
        float out[NB_];
#pragma unroll
        for (int o2 = 0; o2 < NB_; ++o2) {
            float a = b2[o2];
#pragma unroll
            for (int o = 0; o < C1_; ++o) a = fmaf(w2[o2 * C1_ + o], pool[o], a);
            out[o2] = a;
        }
#pragma unroll
        for (int d = 0; d < ND_; ++d) dynb[(t * ND_ + d) * S2_ + s] = out[d];
        if (t == T_ - 1) {
#pragma unroll
            for (int c = 0; c < ND_; ++c) feat[(ND_ + c) * S2_ + s] = out[ND_ + c];
        }
    }
}

// Scrambled-reshape scalar LSTM: sequence p in [0,91204), feature d in [0,5).
// Native exp (v_exp_f32) + rcp instead of libm expf/tanhf.
__global__ __launch_bounds__(256) void k_lstm(const float* __restrict__ dynb,
                                              const float* __restrict__ w_ih,
                                              const float* __restrict__ w_hh,
                                              const float* __restrict__ b_ih,
                                              const float* __restrict__ b_hh,
                                              float* __restrict__ feat) {
    int i = blockIdx.x * 256 + threadIdx.x;
    if (i >= S2_ * ND_) return;
    int p = i / ND_, d = i - p * ND_;

    float wi[4], wh[4], bb[4];
#pragma unroll
    for (int g = 0; g < 4; ++g) {
        wi[g] = w_ih[d * 4 + g];
        wh[g] = w_hh[d * 4 + g];
        bb[g] = b_ih[d * 4 + g] + b_hh[d * 4 + g];
    }
    float h = 0.f, cc = 0.f;
#pragma unroll 1
    for (int tt = 0; tt < T_; ++tt) {
        float xt = dynb[p * (T_ * ND_) + tt * ND_ + d];
        float g0 = fmaf(xt, wi[0], fmaf(h, wh[0], bb[0]));
        float g1 = fmaf(xt, wi[1], fmaf(h, wh[1], bb[1]));
        float g2 = fmaf(xt, wi[2], fmaf(h, wh[2], bb[2]));
        float g3 = fmaf(xt, wi[3], fmaf(h, wh[3], bb[3]));
        float ig = __builtin_amdgcn_rcpf(1.f + __expf(-g0));
        float fg = __builtin_amdgcn_rcpf(1.f + __expf(-g1));
        float gg = fmaf(2.f, __builtin_amdgcn_rcpf(1.f + __expf(-2.f * g2)), -1.f);
        float og = __builtin_amdgcn_rcpf(1.f + __expf(-g3));
        cc = fg * cc + ig * gg;
        float th = fmaf(2.f, __builtin_amdgcn_rcpf(1.f + __expf(-2.f * cc)), -1.f);
        h = og * th;
    }
    feat[d * S2_ + p] = h;
}

// fc1 partial GEMV: grid (446, 2); every thread does EXACTLY 2 i4-iterations
// (second masked at the very tail). Block (bx,jy) accumulates 32 outputs.
__global__ __launch_bounds__(256) void k_fc1(const float* __restrict__ feat,
                                             const float* __restrict__ w,
                                             float* __restrict__ partial) {
    __shared__ float red[4][32];
    const int tid = threadIdx.x;
    const int jbase = blockIdx.y * 32;
    const int NI4 = FLAT_ / 4;                 // 228010
    const int HALF = XBLK_FC1 * 256;           // 114176
    float acc[32];
#pragma unroll
    for (int j = 0; j < 32; ++j) acc[j] = 0.f;
    const float* wb = w + (size_t)jbase * FLAT_;

    int i4a = blockIdx.x * 256 + tid;          // always < NI4
    int i4b = i4a + HALF;                      // mask vs NI4
    {
        f4 f = *(const f4*)(feat + (size_t)i4a * 4);
#pragma unroll
        for (int j = 0; j < 32; ++j) {
            f4 wv = *(const f4*)(wb + (size_t)j * FLAT_ + (size_t)i4a * 4);
            acc[j] = fmaf(wv.x, f.x, acc[j]);
            acc[j] = fmaf(wv.y, f.y, acc[j]);
            acc[j] = fmaf(wv.z, f.z, acc[j]);
            acc[j] = fmaf(wv.w, f.w, acc[j]);
        }
    }
    if (i4b < NI4) {
        f4 f = *(const f4*)(feat + (size_t)i4b * 4);
#pragma unroll
        for (int j = 0; j < 32; ++j) {
            f4 wv = *(const f4*)(wb + (size_t)j * FLAT_ + (size_t)i4b * 4);
            acc[j] = fmaf(wv.x, f.x, acc[j]);
            acc[j] = fmaf(wv.y, f.y, acc[j]);
            acc[j] = fmaf(wv.z, f.z, acc[j]);
            acc[j] = fmaf(wv.w, f.w, acc[j]);
        }
    }
    int lane = tid & 63, wid = tid >> 6;
#pragma unroll
    for (int j = 0; j < 32; ++j) {
        float v = acc[j];
#pragma unroll
        for (int off = 32; off >= 1; off >>= 1) v += __shfl_xor(v, off, 64);
        if (lane == 0) red[wid][j] = v;
    }
    __syncthreads();
    if (tid < 32) {
        float s = red[0][tid] + red[1][tid] + red[2][tid] + red[3][tid];
        partial[blockIdx.x * 64 + jbase + tid] = s;
    }
}

// Final reduce + fc2/relu/fc3/fc4 -> 3 outputs. Single block.
__global__ __launch_bounds__(256) void k_head(const float* __restrict__ partial,
                                              const float* __restrict__ fc1_b,
                                              const float* __restrict__ fc2_w,
                                              const float* __restrict__ fc2_b,
                                              const float* __restrict__ fc3_w,
                                              const float* __restrict__ fc3_b,
                                              const float* __restrict__ fc4_w,
                                              const float* __restrict__ fc4_b,
                                              float* __restrict__ out) {
    __shared__ float r4[256];
    __shared__ float y1[64], y2[64], y3[16];
    int tid = threadIdx.x;
    int j = tid & 63, q = tid >> 6;
    float s = 0.f;
    for (int b = q; b < XBLK_FC1; b += 4) s += partial[b * 64 + j];
    r4[tid] = s;
    __syncthreads();
    if (tid < 64)
        y1[tid] = r4[tid] + r4[64 + tid] + r4[128 + tid] + r4[192 + tid] + fc1_b[tid];
    __syncthreads();
    if (tid < 64) {
        float a = fc2_b[tid];
#pragma unroll
        for (int k = 0; k < 64; ++k) a = fmaf(fc2_w[tid * 64 + k], y1[k], a);
        y2[tid] = fmaxf(a, 0.f);
    }
    __syncthreads();
    if (tid < 16) {
        float a = fc3_b[tid];
#pragma unroll
        for (int k = 0; k < 64; ++k) a = fmaf(fc3_w[tid * 64 + k], y2[k], a);
        y3[tid] = a;
    }
    __syncthreads();
    if (tid < 3) {
        float a = fc4_b[tid];
#pragma unroll
        for (int k = 0; k < 16; ++k) a = fmaf(fc4_w[tid * 16 + k], y3[k], a);
        out[tid] = a;
    }
}

extern "C" void kernel_launch(void* const* d_in, const int* in_sizes, int n_in,
                              void* d_out, int out_size, void* d_ws, size_t ws_size,
                              hipStream_t stream) {
    const float* x     = (const float*)d_in[0];
    const float* w1    = (const float*)d_in[1];
    const float* b1    = (const float*)d_in[2];
    const float* w2    = (const float*)d_in[3];
    const float* b2    = (const float*)d_in[4];
    const float* w_ih  = (const float*)d_in[5];
    const float* w_hh  = (const float*)d_in[6];
    const float* b_ih  = (const float*)d_in[7];
    const float* b_hh  = (const float*)d_in[8];
    const float* fc1_w = (const float*)d_in[9];
    const float* fc1_b = (const float*)d_in[10];
    const float* fc2_w = (const float*)d_in[11];
    const float* fc2_b = (const float*)d_in[12];
    const float* fc3_w = (const float*)d_in[13];
    const float* fc3_b = (const float*)d_in[14];
    const float* fc4_w = (const float*)d_in[15];
    const float* fc4_b = (const float*)d_in[16];

    float* ws      = (float*)d_ws;
    float* dynb    = ws;                          // [10][5][91204]
    float* feat    = ws + (size_t)T_ * ND_ * S2_; // [10][91204]
    float* partial = feat + FLAT_;                // [446][64]

    hipLaunchKernelGGL(k_convpool, dim3(5, 75, T_ + 1), dim3(64, 4), 0, stream,
                       x, w1, b1, w2, b2, dynb, feat);
    hipLaunchKernelGGL(k_lstm, dim3((S2_ * ND_ + 255) / 256), dim3(256), 0, stream,
                       dynb, w_ih, w_hh, b_ih, b_hh, feat);
    hipLaunchKernelGGL(k_fc1, dim3(XBLK_FC1, 2), dim3(256), 0, stream,
                       feat, fc1_w, partial);
    hipLaunchKernelGGL(k_head, dim3(1), dim3(256), 0, stream,
                       partial, fc1_b, fc2_w, fc2_b, fc3_w, fc3_b, fc4_w, fc4_b,
                       (float*)d_out);
}

// Round 7
// 215.831 us; speedup vs baseline: 2.5866x; 1.0456x over previous
//
#include <hip/hip_runtime.h>
#include <math.h>

#define T_    10
#define NB_   10
#define C1_   20            // 2*NB
#define SX_   1200
#define OX_   302
#define S2_   (OX_*OX_)     // 91204
#define NP_   300           // pooled interior size
#define ND_   5
#define FLAT_ (NB_*S2_)     // 912040
#define XBLK_FC1 446        // 446*256*2 = 228352 >= 228010 : exactly 2 iters/thread

typedef float f4 __attribute__((ext_vector_type(4)));
typedef float f2 __attribute__((ext_vector_type(2)));

// Fused: 1x1 conv1 (+zero-pad) -> 4x4 maxpool -> 1x1 conv2 (interior), plus
// border fill on the z==10 grid slice.
// conv1 inner loop: v_pk_fma_f32 (packed over column pairs), weight broadcast
// via op_sel from an SGPR pair; bias deferred past the pool (exact - rounded
// addition is monotone so max(conv)+b == max(conv+b)).
__global__ __launch_bounds__(256, 4) void k_convpool(const float* __restrict__ x,
                                                     const float* __restrict__ w1,
                                                     const float* __restrict__ b1,
                                                     const float* __restrict__ w2,
                                                     const float* __restrict__ b2,
                                                     float* __restrict__ dynb,
                                                     float* __restrict__ feat) {
    const int t = blockIdx.z;
    if (t == T_) {
        // border fill: x5 border pixels have value conv2_b[channel]
        int s = (blockIdx.y * 5 + blockIdx.x) * 256 + threadIdx.y * 64 + threadIdx.x;
        if (s >= S2_) return;
        int ox = s / OX_, oy = s % OX_;
        if (ox != 0 && ox != OX_ - 1 && oy != 0 && oy != OX_ - 1) return;
#pragma unroll
        for (int d = 0; d < ND_; ++d) {
            float v = b2[d];
#pragma unroll
            for (int tt = 0; tt < T_; ++tt) dynb[(tt * ND_ + d) * S2_ + s] = v;
        }
#pragma unroll
        for (int c = 0; c < ND_; ++c) feat[(ND_ + c) * S2_ + s] = b2[ND_ + c];
        return;
    }

    const int lane  = threadIdx.x;                  // 0..63
    const int obase = blockIdx.x * 63;              // 0,63,126,189,252
    const int px    = blockIdx.y * 4 + threadIdx.y; // 0..299

    const int lc  = 4 * (obase - 1 + lane);         // this lane's aligned column base
    const int lcc = lc < 0 ? 0 : (lc > SX_ - 4 ? SX_ - 4 : lc);
    const bool m3valid = (lc >= 0);

    // conv-only (bias-deferred) pooling accumulators
    float pool012[C1_], pool3[C1_];
#pragma unroll
    for (int o = 0; o < C1_; ++o) { pool012[o] = -3.0e38f; pool3[o] = -3.0e38f; }

    const int rs = (px > 0) ? 4 * px - 1 : 0;
    const int re = 4 * px + 2;
    const float* xt = x + (size_t)t * NB_ * SX_ * SX_;
    const f2* w1p = (const f2*)w1;                  // [C1_][5] channel pairs

    for (int row = rs; row <= re; ++row) {
        f4 xq[NB_];
#pragma unroll
        for (int c = 0; c < NB_; ++c)
            xq[c] = *(const f4*)(xt + ((size_t)c * SX_ + row) * SX_ + lcc);
        f2 x01[NB_], x23[NB_];
#pragma unroll
        for (int c = 0; c < NB_; ++c) {
            x01[c] = __builtin_shufflevector(xq[c], xq[c], 0, 1);   // low pair
            x23[c] = __builtin_shufflevector(xq[c], xq[c], 2, 3);   // high pair
        }
#pragma unroll
        for (int o = 0; o < C1_; ++o) {
            f2 h01, h23;
            {   // channel pair 0: c=0 via pk_mul (w.lo bcast), c=1 pk_fma (w.hi bcast)
                f2 w = w1p[o * 5 + 0];
                asm("v_pk_mul_f32 %0, %1, %2 op_sel:[0,0] op_sel_hi:[1,0]"
                    : "=v"(h01) : "v"(x01[0]), "s"(w));
                asm("v_pk_mul_f32 %0, %1, %2 op_sel:[0,0] op_sel_hi:[1,0]"
                    : "=v"(h23) : "v"(x23[0]), "s"(w));
                asm("v_pk_fma_f32 %0, %1, %2, %0 op_sel:[0,1,0] op_sel_hi:[1,1,1]"
                    : "+v"(h01) : "v"(x01[1]), "s"(w));
                asm("v_pk_fma_f32 %0, %1, %2, %0 op_sel:[0,1,0] op_sel_hi:[1,1,1]"
                    : "+v"(h23) : "v"(x23[1]), "s"(w));
            }
#pragma unroll
            for (int c2 = 1; c2 < 5; ++c2) {
                f2 w = w1p[o * 5 + c2];
                asm("v_pk_fma_f32 %0, %1, %2, %0 op_sel:[0,0,0] op_sel_hi:[1,0,1]"
                    : "+v"(h01) : "v"(x01[2 * c2]), "s"(w));
                asm("v_pk_fma_f32 %0, %1, %2, %0 op_sel:[0,0,0] op_sel_hi:[1,0,1]"
                    : "+v"(h23) : "v"(x23[2 * c2]), "s"(w));
                asm("v_pk_fma_f32 %0, %1, %2, %0 op_sel:[0,1,0] op_sel_hi:[1,1,1]"
                    : "+v"(h01) : "v"(x01[2 * c2 + 1]), "s"(w));
                asm("v_pk_fma_f32 %0, %1, %2, %0 op_sel:[0,1,0] op_sel_hi:[1,1,1]"
                    : "+v"(h23) : "v"(x23[2 * c2 + 1]), "s"(w));
            }
            pool012[o] = fmaxf(pool012[o], fmaxf(fmaxf(h01.x, h01.y), h23.x));
            pool3[o]   = fmaxf(pool3[o], h23.y);
        }
    }

    const int py = obase + lane;
    const bool edge = (px == 0) | (py == 0);
    float pool[C1_];
#pragma unroll
    for (int o = 0; o < C1_; ++o) {
        float m3    = m3valid ? pool3[o] : -3.0e38f;
        float other = __shfl_down(pool012[o], 1, 64);   // lane k+1's cols 0..2
        float p = fmaxf(m3, other);
        if (edge) p = fmaxf(p, 0.f);          // zero-pad pixel = 0 in conv-only space
        pool[o] = p + b1[o];                  // deferred conv1 bias (exact)
    }

    if (lane < 63 && py < NP_) {
        int s = (px + 1) * OX_ + (py + 1);
        float out[NB_];
#pragma unroll
        for (int o2 = 0; o2 < NB_; ++o2) {
            float a = b2[o2];
#pragma unroll
            for (int o = 0; o < C1_; ++o) a = fmaf(w2[o2 * C1_ + o], pool[o], a);
            out[o2] = a;
        }
#pragma unroll
        for (int d = 0; d < ND_; ++d) dynb[(t * ND_ + d) * S2_ + s] = out[d];
        if (t == T_ - 1) {
#pragma unroll
            for (int c = 0; c < ND_; ++c) feat[(ND_ + c) * S2_ + s] = out[ND_ + c];
        }
    }
}

// Scrambled-reshape scalar LSTM: sequence p in [0,91204), feature d in [0,5).
// Native exp (v_exp_f32) + rcp instead of libm expf/tanhf.
__global__ __launch_bounds__(256) void k_lstm(const float* __restrict__ dynb,
                                              const float* __restrict__ w_ih,
                                              const float* __restrict__ w_hh,
                                              const float* __restrict__ b_ih,
                                              const float* __restrict__ b_hh,
                                              float* __restrict__ feat) {
    int i = blockIdx.x * 256 + threadIdx.x;
    if (i >= S2_ * ND_) return;
    int p = i / ND_, d = i - p * ND_;

    float wi[4], wh[4], bb[4];
#pragma unroll
    for (int g = 0; g < 4; ++g) {
        wi[g] = w_ih[d * 4 + g];
        wh[g] = w_hh[d * 4 + g];
        bb[g] = b_ih[d * 4 + g] + b_hh[d * 4 + g];
    }
    float h = 0.f, cc = 0.f;
#pragma unroll 1
    for (int tt = 0; tt < T_; ++tt) {
        float xt = dynb[p * (T_ * ND_) + tt * ND_ + d];
        float g0 = fmaf(xt, wi[0], fmaf(h, wh[0], bb[0]));
        float g1 = fmaf(xt, wi[1], fmaf(h, wh[1], bb[1]));
        float g2 = fmaf(xt, wi[2], fmaf(h, wh[2], bb[2]));
        float g3 = fmaf(xt, wi[3], fmaf(h, wh[3], bb[3]));
        float ig = __builtin_amdgcn_rcpf(1.f + __expf(-g0));
        float fg = __builtin_amdgcn_rcpf(1.f + __expf(-g1));
        float gg = fmaf(2.f, __builtin_amdgcn_rcpf(1.f + __expf(-2.f * g2)), -1.f);
        float og = __builtin_amdgcn_rcpf(1.f + __expf(-g3));
        cc = fg * cc + ig * gg;
        float th = fmaf(2.f, __builtin_amdgcn_rcpf(1.f + __expf(-2.f * cc)), -1.f);
        h = og * th;
    }
    feat[d * S2_ + p] = h;
}

// fc1 partial GEMV: grid (446, 2); every thread does EXACTLY 2 i4-iterations
// (second masked at the very tail). Block (bx,jy) accumulates 32 outputs.
__global__ __launch_bounds__(256) void k_fc1(const float* __restrict__ feat,
                                             const float* __restrict__ w,
                                             float* __restrict__ partial) {
    __shared__ float red[4][32];
    const int tid = threadIdx.x;
    const int jbase = blockIdx.y * 32;
    const int NI4 = FLAT_ / 4;                 // 228010
    const int HALF = XBLK_FC1 * 256;           // 114176
    float acc[32];
#pragma unroll
    for (int j = 0; j < 32; ++j) acc[j] = 0.f;
    const float* wb = w + (size_t)jbase * FLAT_;

    int i4a = blockIdx.x * 256 + tid;          // always < NI4
    int i4b = i4a + HALF;                      // mask vs NI4
    {
        f4 f = *(const f4*)(feat + (size_t)i4a * 4);
#pragma unroll
        for (int j = 0; j < 32; ++j) {
            f4 wv = *(const f4*)(wb + (size_t)j * FLAT_ + (size_t)i4a * 4);
            acc[j] = fmaf(wv.x, f.x, acc[j]);
            acc[j] = fmaf(wv.y, f.y, acc[j]);
            acc[j] = fmaf(wv.z, f.z, acc[j]);
            acc[j] = fmaf(wv.w, f.w, acc[j]);
        }
    }
    if (i4b < NI4) {
        f4 f = *(const f4*)(feat + (size_t)i4b * 4);
#pragma unroll
        for (int j = 0; j < 32; ++j) {
            f4 wv = *(const f4*)(wb + (size_t)j * FLAT_ + (size_t)i4b * 4);
            acc[j] = fmaf(wv.x, f.x, acc[j]);
            acc[j] = fmaf(wv.y, f.y, acc[j]);
            acc[j] = fmaf(wv.z, f.z, acc[j]);
            acc[j] = fmaf(wv.w, f.w, acc[j]);
        }
    }
    int lane = tid & 63, wid = tid >> 6;
#pragma unroll
    for (int j = 0; j < 32; ++j) {
        float v = acc[j];
#pragma unroll
        for (int off = 32; off >= 1; off >>= 1) v += __shfl_xor(v, off, 64);
        if (lane == 0) red[wid][j] = v;
    }
    __syncthreads();
    if (tid < 32) {
        float s = red[0][tid] + red[1][tid] + red[2][tid] + red[3][tid];
        partial[blockIdx.x * 64 + jbase + tid] = s;
    }
}

// Final reduce + fc2/relu/fc3/fc4 -> 3 outputs. Single block.
__global__ __launch_bounds__(256) void k_head(const float* __restrict__ partial,
                                              const float* __restrict__ fc1_b,
                                              const float* __restrict__ fc2_w,
                                              const float* __restrict__ fc2_b,
                                              const float* __restrict__ fc3_w,
                                              const float* __restrict__ fc3_b,
                                              const float* __restrict__ fc4_w,
                                              const float* __restrict__ fc4_b,
                                              float* __restrict__ out) {
    __shared__ float r4[256];
    __shared__ float y1[64], y2[64], y3[16];
    int tid = threadIdx.x;
    int j = tid & 63, q = tid >> 6;
    float s = 0.f;
    for (int b = q; b < XBLK_FC1; b += 4) s += partial[b * 64 + j];
    r4[tid] = s;
    __syncthreads();
    if (tid < 64)
        y1[tid] = r4[tid] + r4[64 + tid] + r4[128 + tid] + r4[192 + tid] + fc1_b[tid];
    __syncthreads();
    if (tid < 64) {
        float a = fc2_b[tid];
#pragma unroll
        for (int k = 0; k < 64; ++k) a = fmaf(fc2_w[tid * 64 + k], y1[k], a);
        y2[tid] = fmaxf(a, 0.f);
    }
    __syncthreads();
    if (tid < 16) {
        float a = fc3_b[tid];
#pragma unroll
        for (int k = 0; k < 64; ++k) a = fmaf(fc3_w[tid * 64 + k], y2[k], a);
        y3[tid] = a;
    }
    __syncthreads();
    if (tid < 3) {
        float a = fc4_b[tid];
#pragma unroll
        for (int k = 0; k < 16; ++k) a = fmaf(fc4_w[tid * 16 + k], y3[k], a);
        out[tid] = a;
    }
}

extern "C" void kernel_launch(void* const* d_in, const int* in_sizes, int n_in,
                              void* d_out, int out_size, void* d_ws, size_t ws_size,
                              hipStream_t stream) {
    const float* x     = (const float*)d_in[0];
    const float* w1    = (const float*)d_in[1];
    const float* b1    = (const float*)d_in[2];
    const float* w2    = (const float*)d_in[3];
    const float* b2    = (const float*)d_in[4];
    const float* w_ih  = (const float*)d_in[5];
    const float* w_hh  = (const float*)d_in[6];
    const float* b_ih  = (const float*)d_in[7];
    const float* b_hh  = (const float*)d_in[8];
    const float* fc1_w = (const float*)d_in[9];
    const float* fc1_b = (const float*)d_in[10];
    const float* fc2_w = (const float*)d_in[11];
    const float* fc2_b = (const float*)d_in[12];
    const float* fc3_w = (const float*)d_in[13];
    const float* fc3_b = (const float*)d_in[14];
    const float* fc4_w = (const float*)d_in[15];
    const float* fc4_b = (const float*)d_in[16];

    float* ws      = (float*)d_ws;
    float* dynb    = ws;                          // [10][5][91204]
    float* feat    = ws + (size_t)T_ * ND_ * S2_; // [10][91204]
    float* partial = feat + FLAT_;                // [446][64]

    hipLaunchKernelGGL(k_convpool, dim3(5, 75, T_ + 1), dim3(64, 4), 0, stream,
                       x, w1, b1, w2, b2, dynb, feat);
    hipLaunchKernelGGL(k_lstm, dim3((S2_ * ND_ + 255) / 256), dim3(256), 0, stream,
                       dynb, w_ih, w_hh, b_ih, b_hh, feat);
    hipLaunchKernelGGL(k_fc1, dim3(XBLK_FC1, 2), dim3(256), 0, stream,
                       feat, fc1_w, partial);
    hipLaunchKernelGGL(k_head, dim3(1), dim3(256), 0, stream,
                       partial, fc1_b, fc2_w, fc2_b, fc3_w, fc3_b, fc4_w, fc4_b,
                       (float*)d_out);
}